// Round 8
// baseline (2123.578 us; speedup 1.0000x reference)
//
#include <hip/hip_runtime.h>

#define B 4
#define N 8192
#define H 256
#define E 8192
#define M 2048
#define T_ITERS 8
#define ET 4

typedef __bf16 bf16x8 __attribute__((ext_vector_type(8)));
typedef float f32x4 __attribute__((ext_vector_type(4)));

__device__ __forceinline__ unsigned short f2bf(float x) {
    unsigned u = __float_as_uint(x);
    u += 0x7fffu + ((u >> 16) & 1u);
    return (unsigned short)(u >> 16);
}
__device__ __forceinline__ unsigned packsplit(float x) {
    unsigned hi = f2bf(x);
    float hif = __uint_as_float(hi << 16);
    unsigned lo = f2bf(x - hif);
    return (hi << 16) | lo;
}
__device__ __forceinline__ float unpacksplit(unsigned p) {
    return __uint_as_float(p & 0xffff0000u) + __uint_as_float(p << 16);
}
__device__ __forceinline__ float fsig(float x) { return 1.0f / (1.0f + __expf(-x)); }
__device__ __forceinline__ float ftanh(float x) {
    float cx = fminf(fmaxf(x, -30.0f), 30.0f);
    float t = __expf(2.0f * cx);
    return (t - 1.0f) / (t + 1.0f);
}

__device__ __forceinline__ void unpack8(uint4 a, uint4 b, bf16x8& hi, bf16x8& lo) {
    union U { unsigned u[4]; bf16x8 v; } uh, ul;
    uh.u[0] = (a.x >> 16) | (a.y & 0xffff0000u);
    uh.u[1] = (a.z >> 16) | (a.w & 0xffff0000u);
    uh.u[2] = (b.x >> 16) | (b.y & 0xffff0000u);
    uh.u[3] = (b.z >> 16) | (b.w & 0xffff0000u);
    ul.u[0] = (a.x & 0xffffu) | (a.y << 16);
    ul.u[1] = (a.z & 0xffffu) | (a.w << 16);
    ul.u[2] = (b.x & 0xffffu) | (b.y << 16);
    ul.u[3] = (b.z & 0xffffu) | (b.w << 16);
    hi = uh.v; lo = ul.v;
}
__device__ __forceinline__ void split8(const float4& a, const float4& b, bf16x8& hi, bf16x8& lo) {
    const float v[8] = {a.x, a.y, a.z, a.w, b.x, b.y, b.z, b.w};
    union U { unsigned short s[8]; bf16x8 v; } uh, ul;
    #pragma unroll
    for (int i = 0; i < 8; ++i) {
        const unsigned short h = f2bf(v[i]);
        uh.s[i] = h;
        ul.s[i] = f2bf(v[i] - __uint_as_float(((unsigned)h) << 16));
    }
    hi = uh.v; lo = ul.v;
}

// fp32 -> split bf16 hi/lo pack (initial embedding)
__global__ __launch_bounds__(256) void pack_kernel(
    const float* __restrict__ src, unsigned* __restrict__ dst)
{
    const int i = blockIdx.x * 256 + threadIdx.x;
    const float4 v = ((const float4*)src)[i];
    uint4 o = { packsplit(v.x), packsplit(v.y), packsplit(v.z), packsplit(v.w) };
    ((uint4*)dst)[i] = o;
}

// msg weights -> fragment-major: Wmt[(((e*16+c16)*8+ks)*64+ln)*8+j]
//   = W_msg[e][c16*16+(ln&15)][ks*32+(ln>>4)*8+j]
__global__ __launch_bounds__(256) void wtrans_msg(
    const float* __restrict__ W_msg, __bf16* __restrict__ Wmt)
{
    const int f = blockIdx.x * 256 + threadIdx.x;  // 0..32767
    const int ln = f & 63;
    const int t = (f >> 6) & 7;
    const int c16 = (f >> 9) & 15;
    const int e = f >> 13;
    const int col = c16 * 16 + (ln & 15);
    const int k = t * 32 + (ln >> 4) * 8;
    const float* src = W_msg + ((size_t)e * H + col) * H + k;
    const float4 a = *(const float4*)src;
    const float4 b = *(const float4*)(src + 4);
    ushort4 o0 = { f2bf(a.x), f2bf(a.y), f2bf(a.z), f2bf(a.w) };
    ushort4 o1 = { f2bf(b.x), f2bf(b.y), f2bf(b.z), f2bf(b.w) };
    *(ushort4*)(Wmt + (size_t)f * 8) = o0;
    *(ushort4*)(Wmt + (size_t)f * 8 + 4) = o1;
}

// gate weights -> fragment-major (g 0..2: W_ih r,z,n; 3..5: W_hh r,z,n)
__global__ __launch_bounds__(256) void wtrans_gate(
    const float* __restrict__ W_ih, const float* __restrict__ W_hh,
    __bf16* __restrict__ Wt)
{
    const int f = blockIdx.x * 256 + threadIdx.x;  // 0..49151
    const int ln = f & 63;
    const int t = (f >> 6) & 7;
    const int c16 = (f >> 9) & 15;
    const int g = f >> 13;
    const int col = c16 * 16 + (ln & 15);
    const int k = t * 32 + (ln >> 4) * 8;
    const float* src = (g < 3) ? (W_ih + ((size_t)g * H + col) * H + k)
                               : (W_hh + ((size_t)(g - 3) * H + col) * H + k);
    const float4 a = *(const float4*)src;
    const float4 b = *(const float4*)(src + 4);
    ushort4 o0 = { f2bf(a.x), f2bf(a.y), f2bf(a.z), f2bf(a.w) };
    ushort4 o1 = { f2bf(b.x), f2bf(b.y), f2bf(b.z), f2bf(b.w) };
    *(ushort4*)(Wt + (size_t)f * 8) = o0;
    *(ushort4*)(Wt + (size_t)f * 8 + 4) = o1;
}

// ---- CSR build (once per launch; edges are iteration-invariant) ----
__global__ __launch_bounds__(256) void countk(
    const int* __restrict__ ed0, const int* __restrict__ ed1,
    const int* __restrict__ ed2, const int* __restrict__ ed3,
    int* __restrict__ csr)
{
    const int i = blockIdx.x * 256 + threadIdx.x;  // 0..B*ET*E-1
    const int edge = i & (E - 1);
    const int be = i >> 13;
    const int b = be >> 2, e = be & 3;
    const int* ed = (e == 0) ? ed0 : (e == 1) ? ed1 : (e == 2) ? ed2 : ed3;
    const int tgt = ed[((size_t)b * E + edge) * 2 + 1];
    atomicAdd(&csr[(size_t)be * N + tgt], 1);
}

// in-place exclusive scan per (b,e): csr hist -> start pointers
__global__ __launch_bounds__(256) void scank(int* __restrict__ csr)
{
    int* d = csr + (size_t)blockIdx.x * N;
    const int t = threadIdx.x;
    __shared__ int part[256];
    int loc[32];
    const int base = t * 32;
    int s = 0;
    #pragma unroll
    for (int i = 0; i < 32; ++i) { loc[i] = d[base + i]; s += loc[i]; }
    part[t] = s;
    __syncthreads();
    if (t == 0) { int a = 0; for (int i = 0; i < 256; ++i) { int v = part[i]; part[i] = a; a += v; } }
    __syncthreads();
    int a = part[t];
    #pragma unroll
    for (int i = 0; i < 32; ++i) { d[base + i] = a; a += loc[i]; }
}

// fill: atomicAdd returns the slot; afterwards csr[n] = end[n] (start = csr[n-1])
__global__ __launch_bounds__(256) void fillk(
    const int* __restrict__ ed0, const int* __restrict__ ed1,
    const int* __restrict__ ed2, const int* __restrict__ ed3,
    int* __restrict__ csr, int* __restrict__ eidx)
{
    const int i = blockIdx.x * 256 + threadIdx.x;
    const int edge = i & (E - 1);
    const int be = i >> 13;
    const int b = be >> 2, e = be & 3;
    const int* ed = (e == 0) ? ed0 : (e == 1) ? ed1 : (e == 2) ? ed2 : ed3;
    const int tgt = ed[((size_t)b * E + edge) * 2 + 1];
    const int pos = atomicAdd(&csr[(size_t)be * N + tgt], 1);
    eidx[(size_t)be * E + pos] = edge;
}

// msg GEMM, no atomics: medge[(bl*ET+e)*E+edge][col] = (h[src] @ W_e^T)  (bf16, raw, no bias)
// Block: 64 edges x 256 cols; A (gathered h rows, hi/lo) in LDS, XOR-swizzled.
__global__ __launch_bounds__(256) void msgk2(
    const unsigned* __restrict__ hp,
    const int* __restrict__ ed0, const int* __restrict__ ed1,
    const int* __restrict__ ed2, const int* __restrict__ ed3,
    const __bf16* __restrict__ Wmt, unsigned short* __restrict__ medge,
    const int bc)
{
    __shared__ __bf16 sHi[64 * 256];
    __shared__ __bf16 sLo[64 * 256];
    const int tid = threadIdx.x;
    const int by = blockIdx.y;           // 0..7
    const int bl = by >> 2, e = by & 3;
    const int b = bc * 2 + bl;
    const int* ed = (e == 0) ? ed0 : (e == 1) ? ed1 : (e == 2) ? ed2 : ed3;
    const int row0 = blockIdx.x * 64;

    #pragma unroll
    for (int half = 0; half < 2; ++half) {
        const int r = half * 32 + (tid >> 3);
        const int k0 = (tid & 7) * 32;
        const int src = ed[((size_t)b * E + row0 + r) * 2];
        const unsigned* hrow = hp + ((size_t)b * N + src) * H + k0;
        #pragma unroll
        for (int c = 0; c < 4; ++c) {
            uint4 ha = *(const uint4*)(hrow + c * 8);
            uint4 hb = *(const uint4*)(hrow + c * 8 + 4);
            bf16x8 hi, lo; unpack8(ha, hb, hi, lo);
            const int sc = ((k0 >> 3) + c) ^ (r & 7);
            *(bf16x8*)(sHi + r * 256 + sc * 8) = hi;
            *(bf16x8*)(sLo + r * 256 + sc * 8) = lo;
        }
    }
    __syncthreads();

    const int wv = tid >> 6, ln = tid & 63, lq = ln >> 4, lm = ln & 15;
    f32x4 zero = {0.f, 0.f, 0.f, 0.f};
    f32x4 acc[4][4];  // [mt][nt]
    #pragma unroll
    for (int mt = 0; mt < 4; ++mt)
        #pragma unroll
        for (int nt = 0; nt < 4; ++nt) acc[mt][nt] = zero;

    const __bf16* wbase = Wmt + ((size_t)((e * 16 + wv * 4) * 8)) * 512 + ln * 8;
    bf16x8 Wc[4], Wn[4];
    #pragma unroll
    for (int nt = 0; nt < 4; ++nt)
        Wc[nt] = *(const bf16x8*)(wbase + (size_t)(nt * 8) * 512);

    #pragma unroll
    for (int ks = 0; ks < 8; ++ks) {
        if (ks < 7) {
            #pragma unroll
            for (int nt = 0; nt < 4; ++nt)
                Wn[nt] = *(const bf16x8*)(wbase + (size_t)(nt * 8 + ks + 1) * 512);
        }
        bf16x8 ahi[4], alo[4];
        #pragma unroll
        for (int mt = 0; mt < 4; ++mt) {
            const int r = mt * 16 + lm;
            const int sc = (ks * 4 + lq) ^ (r & 7);
            ahi[mt] = *(const bf16x8*)(sHi + r * 256 + sc * 8);
            alo[mt] = *(const bf16x8*)(sLo + r * 256 + sc * 8);
        }
        #pragma unroll
        for (int nt = 0; nt < 4; ++nt)
            #pragma unroll
            for (int mt = 0; mt < 4; ++mt) {
                acc[mt][nt] = __builtin_amdgcn_mfma_f32_16x16x32_bf16(ahi[mt], Wc[nt], acc[mt][nt], 0, 0, 0);
                acc[mt][nt] = __builtin_amdgcn_mfma_f32_16x16x32_bf16(alo[mt], Wc[nt], acc[mt][nt], 0, 0, 0);
            }
        #pragma unroll
        for (int nt = 0; nt < 4; ++nt) Wc[nt] = Wn[nt];
    }

    unsigned short* mb = medge + ((size_t)(bl * ET + e) * E + row0) * H;
    #pragma unroll
    for (int mt = 0; mt < 4; ++mt)
        #pragma unroll
        for (int rr = 0; rr < 4; ++rr) {
            const int row = mt * 16 + lq * 4 + rr;
            #pragma unroll
            for (int nt = 0; nt < 4; ++nt) {
                const int col = wv * 64 + nt * 16 + lm;
                mb[(size_t)row * H + col] = f2bf(acc[mt][nt][rr]);
            }
        }
}

// Fused gather + GRU, in-place h update. Block = 16 rows x 256 cols.
// Staging walks CSR, sums medge rows + cnt*b_msg into x (fp32), splits to
// bf16 hi/lo LDS planes; h staged as hi/lo planes. Weight sweep g-outer,
// frag-major, double-buffered.
__global__ __launch_bounds__(256) void gruk(
    const unsigned short* __restrict__ medge, const int* __restrict__ csr,
    const int* __restrict__ eidx, const float* __restrict__ b_msg,
    unsigned* __restrict__ hp, const __bf16* __restrict__ Wt,
    const float* __restrict__ b_ih, const float* __restrict__ b_hh,
    const int bc)
{
    __shared__ __bf16 sA[4 * 16 * 256];  // 32768 B: xhi, xlo, hhi, hlo

    const int tid = threadIdx.x;
    const size_t grow0 = (size_t)bc * 2 * N + (size_t)blockIdx.x * 16;

    {
        const int r = tid >> 4;           // 0..15
        const int k0 = (tid & 15) * 16;   // 16 k per thread
        const size_t grow = grow0 + r;
        const int b = (int)(grow >> 13);
        const int nn = (int)(grow & (N - 1));
        const int bl = b - bc * 2;

        float xs[16];
        #pragma unroll
        for (int j = 0; j < 16; ++j) xs[j] = 0.f;
        #pragma unroll
        for (int e = 0; e < ET; ++e) {
            const size_t cbase = (size_t)(b * ET + e) * N;
            const int end = csr[cbase + nn];
            const int start = nn ? csr[cbase + nn - 1] : 0;
            for (int i = start; i < end; ++i) {
                const int eix = eidx[(size_t)(b * ET + e) * E + i];
                const unsigned short* mrow =
                    medge + ((size_t)(bl * ET + e) * E + eix) * H + k0;
                #pragma unroll
                for (int j = 0; j < 16; j += 4) {
                    const ushort4 v = *(const ushort4*)(mrow + j);
                    xs[j + 0] += __uint_as_float((unsigned)v.x << 16);
                    xs[j + 1] += __uint_as_float((unsigned)v.y << 16);
                    xs[j + 2] += __uint_as_float((unsigned)v.z << 16);
                    xs[j + 3] += __uint_as_float((unsigned)v.w << 16);
                }
            }
            const float fc = (float)(end - start);
            const float* bm = b_msg + e * H + k0;
            #pragma unroll
            for (int j = 0; j < 16; j += 4) {
                const float4 bv = *(const float4*)(bm + j);
                xs[j + 0] += fc * bv.x; xs[j + 1] += fc * bv.y;
                xs[j + 2] += fc * bv.z; xs[j + 3] += fc * bv.w;
            }
        }

        const unsigned* hr = hp + grow * H + k0;
        #pragma unroll
        for (int c = 0; c < 2; ++c) {
            float4 xa = { xs[c*8+0], xs[c*8+1], xs[c*8+2], xs[c*8+3] };
            float4 xb = { xs[c*8+4], xs[c*8+5], xs[c*8+6], xs[c*8+7] };
            bf16x8 xhi, xlo; split8(xa, xb, xhi, xlo);
            uint4 ha = *(const uint4*)(hr + c * 8);
            uint4 hb = *(const uint4*)(hr + c * 8 + 4);
            bf16x8 hhi, hlo; unpack8(ha, hb, hhi, hlo);
            const int sc = ((k0 >> 3) + c) ^ (r & 7);
            __bf16* base = sA + r * 256 + sc * 8;
            *(bf16x8*)(base)         = xhi;
            *(bf16x8*)(base + 4096)  = xlo;
            *(bf16x8*)(base + 8192)  = hhi;
            *(bf16x8*)(base + 12288) = hlo;
        }
    }
    __syncthreads();

    const int wv = tid >> 6, ln = tid & 63, lq = ln >> 4, lm = ln & 15;
    f32x4 zero = {0.f, 0.f, 0.f, 0.f};
    f32x4 st[6][4];

    #pragma unroll
    for (int g = 0; g < 6; ++g) {
        const __bf16* wb = Wt + ((size_t)((g * 16 + wv * 4) * 8)) * 512 + ln * 8;
        bf16x8 Wc[4], Wn[4];
        #pragma unroll
        for (int nt = 0; nt < 4; ++nt)
            Wc[nt] = *(const bf16x8*)(wb + (size_t)(nt * 8) * 512);
        f32x4 a[4] = {zero, zero, zero, zero};
        #pragma unroll
        for (int ks = 0; ks < 8; ++ks) {
            if (ks < 7) {
                #pragma unroll
                for (int nt = 0; nt < 4; ++nt)
                    Wn[nt] = *(const bf16x8*)(wb + (size_t)(nt * 8 + ks + 1) * 512);
            }
            const int sc = (ks * 4 + lq) ^ (lm & 7);
            const __bf16* abase = sA + lm * 256 + sc * 8;
            const int poff = (g < 3) ? 0 : 8192;
            const bf16x8 ahi = *(const bf16x8*)(abase + poff);
            const bf16x8 alo = *(const bf16x8*)(abase + poff + 4096);
            #pragma unroll
            for (int nt = 0; nt < 4; ++nt) {
                a[nt] = __builtin_amdgcn_mfma_f32_16x16x32_bf16(ahi, Wc[nt], a[nt], 0, 0, 0);
                a[nt] = __builtin_amdgcn_mfma_f32_16x16x32_bf16(alo, Wc[nt], a[nt], 0, 0, 0);
            }
            #pragma unroll
            for (int nt = 0; nt < 4; ++nt) Wc[nt] = Wn[nt];
        }
        #pragma unroll
        for (int nt = 0; nt < 4; ++nt) st[g][nt] = a[nt];
    }

    // fused gates + in-place split-pack store
    #pragma unroll
    for (int nt = 0; nt < 4; ++nt) {
        const int col = wv * 64 + nt * 16 + lm;
        const float bi_r = b_ih[col], bi_z = b_ih[H + col], bi_n = b_ih[2 * H + col];
        const float bh_r = b_hh[col], bh_z = b_hh[H + col], bh_n = b_hh[2 * H + col];
        #pragma unroll
        for (int rr = 0; rr < 4; ++rr) {
            const size_t row = grow0 + lq * 4 + rr;
            const float hold = unpacksplit(hp[row * H + col]);
            const float rg = fsig(st[0][nt][rr] + bi_r + st[3][nt][rr] + bh_r);
            const float zg = fsig(st[1][nt][rr] + bi_z + st[4][nt][rr] + bh_z);
            const float ng = ftanh(st[2][nt][rr] + bi_n + rg * (st[5][nt][rr] + bh_n));
            const float o = (1.0f - zg) * ng + zg * hold;
            hp[row * H + col] = packsplit(o);
        }
    }
}

__global__ __launch_bounds__(256) void sel_kernel(
    const unsigned* __restrict__ hpack, const int* __restrict__ nao,
    float* __restrict__ out)
{
    const int row = blockIdx.x * 4 + (threadIdx.x >> 6);
    const int lane = threadIdx.x & 63;
    const int b = row >> 11;  // M = 2048
    const int idx = nao[row];
    const uint4 p = ((const uint4*)(hpack + ((size_t)b * N + idx) * H))[lane];
    float4 v = { unpacksplit(p.x), unpacksplit(p.y), unpacksplit(p.z), unpacksplit(p.w) };
    ((float4*)(out + (size_t)row * H))[lane] = v;
}

__global__ __launch_bounds__(256) void gmean_kernel(
    const float* __restrict__ sel, float* __restrict__ gacc)
{
    const int b = blockIdx.x >> 4;
    const int c = blockIdx.x & 15;
    const int j = threadIdx.x;
    float s = 0.0f;
    const float* base = sel + ((size_t)b * M + (size_t)c * 128) * H + j;
    for (int m = 0; m < 128; ++m) s += base[(size_t)m * H];
    atomicAdd(&gacc[b * H + j], s);
}

__global__ __launch_bounds__(256) void final_kernel(
    const float* __restrict__ gacc, float* __restrict__ out)
{
    const int i = blockIdx.x * 256 + threadIdx.x;
    const size_t sel_sz = (size_t)B * M * H;
    if (i < B * M) {
        out[sel_sz + i] = 1.0f;
    } else {
        const int j = i - B * M;
        out[sel_sz + B * M + j] = tanhf(gacc[j] * (1.0f / (float)M));
    }
}

extern "C" void kernel_launch(void* const* d_in, const int* in_sizes, int n_in,
                              void* d_out, int out_size, void* d_ws, size_t ws_size,
                              hipStream_t stream) {
    const float* emb  = (const float*)d_in[0];
    const int*   nao  = (const int*)d_in[2];
    const int*   ed0  = (const int*)d_in[3];
    const int*   ed1  = (const int*)d_in[4];
    const int*   ed2  = (const int*)d_in[5];
    const int*   ed3  = (const int*)d_in[6];
    const float* W_msg = (const float*)d_in[7];
    const float* b_msg = (const float*)d_in[8];
    const float* W_ih  = (const float*)d_in[9];
    const float* W_hh  = (const float*)d_in[10];
    const float* b_ih  = (const float*)d_in[11];
    const float* b_hh  = (const float*)d_in[12];
    float* out = (float*)d_out;

    const size_t helems = (size_t)B * N * H;       // 8.39M

    // ws layout (~69.5 MB total)
    unsigned*       hp    = (unsigned*)d_ws;                              // 33.55 MB
    unsigned short* medge = (unsigned short*)(hp + helems);               // 33.55 MB (2 batches)
    __bf16*   Wmt  = (__bf16*)(medge + (size_t)2 * ET * E * H);           // 0.52 MB
    __bf16*   Wt   = Wmt + (size_t)ET * 16 * 8 * 64 * 8;                  // 0.79 MB
    int*      csr  = (int*)(Wt + (size_t)6 * 16 * 8 * 64 * 8);            // 0.52 MB
    int*      eidx = csr + (size_t)B * ET * N;                            // 0.52 MB
    float*    gacc = (float*)(eidx + (size_t)B * ET * E);                 // 4 KB

    // ---- setup ----
    pack_kernel<<<dim3(helems / 4 / 256), 256, 0, stream>>>(emb, hp);
    wtrans_msg<<<dim3(128), 256, 0, stream>>>(W_msg, Wmt);
    wtrans_gate<<<dim3(192), 256, 0, stream>>>(W_ih, W_hh, Wt);
    hipMemsetAsync(csr, 0, (size_t)B * ET * N * sizeof(int), stream);
    countk<<<dim3(B * ET * E / 256), 256, 0, stream>>>(ed0, ed1, ed2, ed3, csr);
    scank<<<dim3(B * ET), 256, 0, stream>>>(csr);
    fillk<<<dim3(B * ET * E / 256), 256, 0, stream>>>(ed0, ed1, ed2, ed3, csr, eidx);

    // ---- T iterations, 2-batch chunks ----
    for (int t = 0; t < T_ITERS; ++t) {
        for (int bc = 0; bc < 2; ++bc) {
            msgk2<<<dim3(E / 64, 2 * ET), 256, 0, stream>>>(
                hp, ed0, ed1, ed2, ed3, Wmt, medge, bc);
            gruk<<<dim3(2 * N / 16), 256, 0, stream>>>(
                medge, csr, eidx, b_msg, hp, Wt, b_ih, b_hh, bc);
        }
    }

    // ---- epilogue ----
    hipMemsetAsync(gacc, 0, (size_t)B * H * sizeof(float), stream);
    sel_kernel<<<dim3(B * M / 4), 256, 0, stream>>>(hp, nao, out);
    gmean_kernel<<<dim3(B * 16), 256, 0, stream>>>(out, gacc);
    final_kernel<<<dim3((B * M + B * H) / 256), 256, 0, stream>>>(gacc, out);
}

// Round 9
// 1926.878 us; speedup vs baseline: 1.1021x; 1.1021x over previous
//
#include <hip/hip_runtime.h>

#define B 4
#define N 8192
#define H 256
#define E 8192
#define M 2048
#define T_ITERS 8
#define ET 4

typedef __bf16 bf16x8 __attribute__((ext_vector_type(8)));
typedef float f32x4 __attribute__((ext_vector_type(4)));

__device__ __forceinline__ unsigned short f2bf(float x) {
    unsigned u = __float_as_uint(x);
    u += 0x7fffu + ((u >> 16) & 1u);
    return (unsigned short)(u >> 16);
}
__device__ __forceinline__ unsigned packsplit(float x) {
    unsigned hi = f2bf(x);
    float hif = __uint_as_float(hi << 16);
    unsigned lo = f2bf(x - hif);
    return (hi << 16) | lo;
}
__device__ __forceinline__ float unpacksplit(unsigned p) {
    return __uint_as_float(p & 0xffff0000u) + __uint_as_float(p << 16);
}
__device__ __forceinline__ float fsig(float x) { return 1.0f / (1.0f + __expf(-x)); }
__device__ __forceinline__ float ftanh(float x) {
    float cx = fminf(fmaxf(x, -30.0f), 30.0f);
    float t = __expf(2.0f * cx);
    return (t - 1.0f) / (t + 1.0f);
}

__device__ __forceinline__ void unpack8(uint4 a, uint4 b, bf16x8& hi, bf16x8& lo) {
    union U { unsigned u[4]; bf16x8 v; } uh, ul;
    uh.u[0] = (a.x >> 16) | (a.y & 0xffff0000u);
    uh.u[1] = (a.z >> 16) | (a.w & 0xffff0000u);
    uh.u[2] = (b.x >> 16) | (b.y & 0xffff0000u);
    uh.u[3] = (b.z >> 16) | (b.w & 0xffff0000u);
    ul.u[0] = (a.x & 0xffffu) | (a.y << 16);
    ul.u[1] = (a.z & 0xffffu) | (a.w << 16);
    ul.u[2] = (b.x & 0xffffu) | (b.y << 16);
    ul.u[3] = (b.z & 0xffffu) | (b.w << 16);
    hi = uh.v; lo = ul.v;
}
__device__ __forceinline__ void split8(const float4& a, const float4& b, bf16x8& hi, bf16x8& lo) {
    const float v[8] = {a.x, a.y, a.z, a.w, b.x, b.y, b.z, b.w};
    union U { unsigned short s[8]; bf16x8 v; } uh, ul;
    #pragma unroll
    for (int i = 0; i < 8; ++i) {
        const unsigned short h = f2bf(v[i]);
        uh.s[i] = h;
        ul.s[i] = f2bf(v[i] - __uint_as_float(((unsigned)h) << 16));
    }
    hi = uh.v; lo = ul.v;
}

// fp32 -> split bf16 hi/lo pack (initial embedding)
__global__ __launch_bounds__(256) void pack_kernel(
    const float* __restrict__ src, unsigned* __restrict__ dst)
{
    const int i = blockIdx.x * 256 + threadIdx.x;
    const float4 v = ((const float4*)src)[i];
    uint4 o = { packsplit(v.x), packsplit(v.y), packsplit(v.z), packsplit(v.w) };
    ((uint4*)dst)[i] = o;
}

// msg weights -> fragment-major
__global__ __launch_bounds__(256) void wtrans_msg(
    const float* __restrict__ W_msg, __bf16* __restrict__ Wmt)
{
    const int f = blockIdx.x * 256 + threadIdx.x;  // 0..32767
    const int ln = f & 63;
    const int t = (f >> 6) & 7;
    const int c16 = (f >> 9) & 15;
    const int e = f >> 13;
    const int col = c16 * 16 + (ln & 15);
    const int k = t * 32 + (ln >> 4) * 8;
    const float* src = W_msg + ((size_t)e * H + col) * H + k;
    const float4 a = *(const float4*)src;
    const float4 b = *(const float4*)(src + 4);
    ushort4 o0 = { f2bf(a.x), f2bf(a.y), f2bf(a.z), f2bf(a.w) };
    ushort4 o1 = { f2bf(b.x), f2bf(b.y), f2bf(b.z), f2bf(b.w) };
    *(ushort4*)(Wmt + (size_t)f * 8) = o0;
    *(ushort4*)(Wmt + (size_t)f * 8 + 4) = o1;
}

// gate weights -> fragment-major (g 0..2: W_ih r,z,n; 3..5: W_hh r,z,n)
__global__ __launch_bounds__(256) void wtrans_gate(
    const float* __restrict__ W_ih, const float* __restrict__ W_hh,
    __bf16* __restrict__ Wt)
{
    const int f = blockIdx.x * 256 + threadIdx.x;  // 0..49151
    const int ln = f & 63;
    const int t = (f >> 6) & 7;
    const int c16 = (f >> 9) & 15;
    const int g = f >> 13;
    const int col = c16 * 16 + (ln & 15);
    const int k = t * 32 + (ln >> 4) * 8;
    const float* src = (g < 3) ? (W_ih + ((size_t)g * H + col) * H + k)
                               : (W_hh + ((size_t)(g - 3) * H + col) * H + k);
    const float4 a = *(const float4*)src;
    const float4 b = *(const float4*)(src + 4);
    ushort4 o0 = { f2bf(a.x), f2bf(a.y), f2bf(a.z), f2bf(a.w) };
    ushort4 o1 = { f2bf(b.x), f2bf(b.y), f2bf(b.z), f2bf(b.w) };
    *(ushort4*)(Wt + (size_t)f * 8) = o0;
    *(ushort4*)(Wt + (size_t)f * 8 + 4) = o1;
}

// ---- combined CSR build: one list per (b, node), all 4 edge-types ----
__global__ __launch_bounds__(256) void countk2(
    const int* __restrict__ ed0, const int* __restrict__ ed1,
    const int* __restrict__ ed2, const int* __restrict__ ed3,
    int* __restrict__ csrn)
{
    const int i = blockIdx.x * 256 + threadIdx.x;  // 0..B*ET*E-1
    const int edge = i & (E - 1);
    const int be = i >> 13;
    const int b = be >> 2, e = be & 3;
    const int* ed = (e == 0) ? ed0 : (e == 1) ? ed1 : (e == 2) ? ed2 : ed3;
    const int tgt = ed[((size_t)b * E + edge) * 2 + 1];
    atomicAdd(&csrn[(size_t)b * N + tgt], 1);
}

// in-place exclusive scan per batch: hist -> start pointers
__global__ __launch_bounds__(256) void scank(int* __restrict__ csr)
{
    int* d = csr + (size_t)blockIdx.x * N;
    const int t = threadIdx.x;
    __shared__ int part[256];
    int loc[32];
    const int base = t * 32;
    int s = 0;
    #pragma unroll
    for (int i = 0; i < 32; ++i) { loc[i] = d[base + i]; s += loc[i]; }
    part[t] = s;
    __syncthreads();
    if (t == 0) { int a = 0; for (int i = 0; i < 256; ++i) { int v = part[i]; part[i] = a; a += v; } }
    __syncthreads();
    int a = part[t];
    #pragma unroll
    for (int i = 0; i < 32; ++i) { d[base + i] = a; a += loc[i]; }
}

// fill: atomicAdd returns slot; eslot[(b*ET+e)*E+edge] = slot in [0, ET*E).
// Afterwards csrn[b*N+n] = end (start = csrn[b*N+n-1]).
__global__ __launch_bounds__(256) void fillk2(
    const int* __restrict__ ed0, const int* __restrict__ ed1,
    const int* __restrict__ ed2, const int* __restrict__ ed3,
    int* __restrict__ csrn, int* __restrict__ eslot)
{
    const int i = blockIdx.x * 256 + threadIdx.x;
    const int edge = i & (E - 1);
    const int be = i >> 13;
    const int b = be >> 2, e = be & 3;
    const int* ed = (e == 0) ? ed0 : (e == 1) ? ed1 : (e == 2) ? ed2 : ed3;
    const int tgt = ed[((size_t)b * E + edge) * 2 + 1];
    const int pos = atomicAdd(&csrn[(size_t)b * N + tgt], 1);
    eslot[i] = pos;
}

// msg GEMM: message row (h[src] @ W_e^T + b_e) written bf16 directly into its
// combined-CSR slot -> gather becomes a contiguous stream.
__global__ __launch_bounds__(256) void msgk2(
    const unsigned* __restrict__ hp,
    const int* __restrict__ ed0, const int* __restrict__ ed1,
    const int* __restrict__ ed2, const int* __restrict__ ed3,
    const int* __restrict__ eslot,
    const __bf16* __restrict__ Wmt, const float* __restrict__ b_msg,
    unsigned short* __restrict__ medge, const int bc)
{
    __shared__ __bf16 sHi[64 * 256];
    __shared__ __bf16 sLo[64 * 256];
    __shared__ int s_slot[64];
    const int tid = threadIdx.x;
    const int by = blockIdx.y;           // 0..7
    const int bl = by >> 2, e = by & 3;
    const int b = bc * 2 + bl;
    const int* ed = (e == 0) ? ed0 : (e == 1) ? ed1 : (e == 2) ? ed2 : ed3;
    const int row0 = blockIdx.x * 64;

    if (tid < 64) s_slot[tid] = eslot[(size_t)(b * ET + e) * E + row0 + tid];

    #pragma unroll
    for (int half = 0; half < 2; ++half) {
        const int r = half * 32 + (tid >> 3);
        const int k0 = (tid & 7) * 32;
        const int src = ed[((size_t)b * E + row0 + r) * 2];
        const unsigned* hrow = hp + ((size_t)b * N + src) * H + k0;
        #pragma unroll
        for (int c = 0; c < 4; ++c) {
            uint4 ha = *(const uint4*)(hrow + c * 8);
            uint4 hb = *(const uint4*)(hrow + c * 8 + 4);
            bf16x8 hi, lo; unpack8(ha, hb, hi, lo);
            const int sc = ((k0 >> 3) + c) ^ (r & 7);
            *(bf16x8*)(sHi + r * 256 + sc * 8) = hi;
            *(bf16x8*)(sLo + r * 256 + sc * 8) = lo;
        }
    }
    __syncthreads();

    const int wv = tid >> 6, ln = tid & 63, lq = ln >> 4, lm = ln & 15;
    f32x4 zero = {0.f, 0.f, 0.f, 0.f};
    f32x4 acc[4][4];  // [mt][nt]
    #pragma unroll
    for (int mt = 0; mt < 4; ++mt)
        #pragma unroll
        for (int nt = 0; nt < 4; ++nt) acc[mt][nt] = zero;

    const __bf16* wbase = Wmt + ((size_t)((e * 16 + wv * 4) * 8)) * 512 + ln * 8;
    bf16x8 Wc[4], Wn[4];
    #pragma unroll
    for (int nt = 0; nt < 4; ++nt)
        Wc[nt] = *(const bf16x8*)(wbase + (size_t)(nt * 8) * 512);

    #pragma unroll
    for (int ks = 0; ks < 8; ++ks) {
        if (ks < 7) {
            #pragma unroll
            for (int nt = 0; nt < 4; ++nt)
                Wn[nt] = *(const bf16x8*)(wbase + (size_t)(nt * 8 + ks + 1) * 512);
        }
        bf16x8 ahi[4], alo[4];
        #pragma unroll
        for (int mt = 0; mt < 4; ++mt) {
            const int r = mt * 16 + lm;
            const int sc = (ks * 4 + lq) ^ (r & 7);
            ahi[mt] = *(const bf16x8*)(sHi + r * 256 + sc * 8);
            alo[mt] = *(const bf16x8*)(sLo + r * 256 + sc * 8);
        }
        #pragma unroll
        for (int nt = 0; nt < 4; ++nt)
            #pragma unroll
            for (int mt = 0; mt < 4; ++mt) {
                acc[mt][nt] = __builtin_amdgcn_mfma_f32_16x16x32_bf16(ahi[mt], Wc[nt], acc[mt][nt], 0, 0, 0);
                acc[mt][nt] = __builtin_amdgcn_mfma_f32_16x16x32_bf16(alo[mt], Wc[nt], acc[mt][nt], 0, 0, 0);
            }
        #pragma unroll
        for (int nt = 0; nt < 4; ++nt) Wc[nt] = Wn[nt];
    }

    float bias[4];
    #pragma unroll
    for (int nt = 0; nt < 4; ++nt)
        bias[nt] = b_msg[e * H + wv * 64 + nt * 16 + lm];

    unsigned short* mb = medge + (size_t)bl * (ET * E) * H;
    #pragma unroll
    for (int mt = 0; mt < 4; ++mt)
        #pragma unroll
        for (int rr = 0; rr < 4; ++rr) {
            const int slot = s_slot[mt * 16 + lq * 4 + rr];
            #pragma unroll
            for (int nt = 0; nt < 4; ++nt) {
                const int col = wv * 64 + nt * 16 + lm;
                mb[(size_t)slot * H + col] = f2bf(acc[mt][nt][rr] + bias[nt]);
            }
        }
}

// Fused gather + GRU, in-place h update. Block = 16 rows x 256 cols.
// Staging: 2 bounds loads, then a CONTIGUOUS stream of medge rows (bias
// already folded in). GEMM: g-outer frag-major weights, double-buffered.
__global__ __launch_bounds__(256) void gruk(
    const unsigned short* __restrict__ medge, const int* __restrict__ csrn,
    unsigned* __restrict__ hp, const __bf16* __restrict__ Wt,
    const float* __restrict__ b_ih, const float* __restrict__ b_hh,
    const int bc)
{
    __shared__ __bf16 sA[4 * 16 * 256];  // 32768 B: xhi, xlo, hhi, hlo

    const int tid = threadIdx.x;
    const size_t grow0 = (size_t)bc * 2 * N + (size_t)blockIdx.x * 16;

    {
        const int r = tid >> 4;           // 0..15
        const int k0 = (tid & 15) * 16;   // 16 k per thread
        const size_t grow = grow0 + r;
        const int b = (int)(grow >> 13);
        const int nn = (int)(grow & (N - 1));
        const int bl = b - bc * 2;

        const int end = csrn[(size_t)b * N + nn];
        const int start = nn ? csrn[(size_t)b * N + nn - 1] : 0;

        float xs[16];
        #pragma unroll
        for (int j = 0; j < 16; ++j) xs[j] = 0.f;
        const unsigned short* mbase = medge + (size_t)bl * (ET * E) * H + k0;
        for (int i = start; i < end; ++i) {
            const unsigned short* mrow = mbase + (size_t)i * H;
            #pragma unroll
            for (int j = 0; j < 16; j += 4) {
                const ushort4 v = *(const ushort4*)(mrow + j);
                xs[j + 0] += __uint_as_float((unsigned)v.x << 16);
                xs[j + 1] += __uint_as_float((unsigned)v.y << 16);
                xs[j + 2] += __uint_as_float((unsigned)v.z << 16);
                xs[j + 3] += __uint_as_float((unsigned)v.w << 16);
            }
        }

        const unsigned* hr = hp + grow * H + k0;
        #pragma unroll
        for (int c = 0; c < 2; ++c) {
            float4 xa = { xs[c*8+0], xs[c*8+1], xs[c*8+2], xs[c*8+3] };
            float4 xb = { xs[c*8+4], xs[c*8+5], xs[c*8+6], xs[c*8+7] };
            bf16x8 xhi, xlo; split8(xa, xb, xhi, xlo);
            uint4 ha = *(const uint4*)(hr + c * 8);
            uint4 hb = *(const uint4*)(hr + c * 8 + 4);
            bf16x8 hhi, hlo; unpack8(ha, hb, hhi, hlo);
            const int sc = ((k0 >> 3) + c) ^ (r & 7);
            __bf16* base = sA + r * 256 + sc * 8;
            *(bf16x8*)(base)         = xhi;
            *(bf16x8*)(base + 4096)  = xlo;
            *(bf16x8*)(base + 8192)  = hhi;
            *(bf16x8*)(base + 12288) = hlo;
        }
    }
    __syncthreads();

    const int wv = tid >> 6, ln = tid & 63, lq = ln >> 4, lm = ln & 15;
    f32x4 zero = {0.f, 0.f, 0.f, 0.f};
    f32x4 st[6][4];

    #pragma unroll
    for (int g = 0; g < 6; ++g) {
        const __bf16* wb = Wt + ((size_t)((g * 16 + wv * 4) * 8)) * 512 + ln * 8;
        bf16x8 Wc[4], Wn[4];
        #pragma unroll
        for (int nt = 0; nt < 4; ++nt)
            Wc[nt] = *(const bf16x8*)(wb + (size_t)(nt * 8) * 512);
        f32x4 a[4] = {zero, zero, zero, zero};
        #pragma unroll
        for (int ks = 0; ks < 8; ++ks) {
            if (ks < 7) {
                #pragma unroll
                for (int nt = 0; nt < 4; ++nt)
                    Wn[nt] = *(const bf16x8*)(wb + (size_t)(nt * 8 + ks + 1) * 512);
            }
            const int sc = (ks * 4 + lq) ^ (lm & 7);
            const __bf16* abase = sA + lm * 256 + sc * 8;
            const int poff = (g < 3) ? 0 : 8192;
            const bf16x8 ahi = *(const bf16x8*)(abase + poff);
            const bf16x8 alo = *(const bf16x8*)(abase + poff + 4096);
            #pragma unroll
            for (int nt = 0; nt < 4; ++nt) {
                a[nt] = __builtin_amdgcn_mfma_f32_16x16x32_bf16(ahi, Wc[nt], a[nt], 0, 0, 0);
                a[nt] = __builtin_amdgcn_mfma_f32_16x16x32_bf16(alo, Wc[nt], a[nt], 0, 0, 0);
            }
            #pragma unroll
            for (int nt = 0; nt < 4; ++nt) Wc[nt] = Wn[nt];
        }
        #pragma unroll
        for (int nt = 0; nt < 4; ++nt) st[g][nt] = a[nt];
    }

    // fused gates + in-place split-pack store
    #pragma unroll
    for (int nt = 0; nt < 4; ++nt) {
        const int col = wv * 64 + nt * 16 + lm;
        const float bi_r = b_ih[col], bi_z = b_ih[H + col], bi_n = b_ih[2 * H + col];
        const float bh_r = b_hh[col], bh_z = b_hh[H + col], bh_n = b_hh[2 * H + col];
        #pragma unroll
        for (int rr = 0; rr < 4; ++rr) {
            const size_t row = grow0 + lq * 4 + rr;
            const float hold = unpacksplit(hp[row * H + col]);
            const float rg = fsig(st[0][nt][rr] + bi_r + st[3][nt][rr] + bh_r);
            const float zg = fsig(st[1][nt][rr] + bi_z + st[4][nt][rr] + bh_z);
            const float ng = ftanh(st[2][nt][rr] + bi_n + rg * (st[5][nt][rr] + bh_n));
            const float o = (1.0f - zg) * ng + zg * hold;
            hp[row * H + col] = packsplit(o);
        }
    }
}

__global__ __launch_bounds__(256) void sel_kernel(
    const unsigned* __restrict__ hpack, const int* __restrict__ nao,
    float* __restrict__ out)
{
    const int row = blockIdx.x * 4 + (threadIdx.x >> 6);
    const int lane = threadIdx.x & 63;
    const int b = row >> 11;  // M = 2048
    const int idx = nao[row];
    const uint4 p = ((const uint4*)(hpack + ((size_t)b * N + idx) * H))[lane];
    float4 v = { unpacksplit(p.x), unpacksplit(p.y), unpacksplit(p.z), unpacksplit(p.w) };
    ((float4*)(out + (size_t)row * H))[lane] = v;
}

__global__ __launch_bounds__(256) void gmean_kernel(
    const float* __restrict__ sel, float* __restrict__ gacc)
{
    const int b = blockIdx.x >> 4;
    const int c = blockIdx.x & 15;
    const int j = threadIdx.x;
    float s = 0.0f;
    const float* base = sel + ((size_t)b * M + (size_t)c * 128) * H + j;
    for (int m = 0; m < 128; ++m) s += base[(size_t)m * H];
    atomicAdd(&gacc[b * H + j], s);
}

__global__ __launch_bounds__(256) void final_kernel(
    const float* __restrict__ gacc, float* __restrict__ out)
{
    const int i = blockIdx.x * 256 + threadIdx.x;
    const size_t sel_sz = (size_t)B * M * H;
    if (i < B * M) {
        out[sel_sz + i] = 1.0f;
    } else {
        const int j = i - B * M;
        out[sel_sz + B * M + j] = tanhf(gacc[j] * (1.0f / (float)M));
    }
}

extern "C" void kernel_launch(void* const* d_in, const int* in_sizes, int n_in,
                              void* d_out, int out_size, void* d_ws, size_t ws_size,
                              hipStream_t stream) {
    const float* emb  = (const float*)d_in[0];
    const int*   nao  = (const int*)d_in[2];
    const int*   ed0  = (const int*)d_in[3];
    const int*   ed1  = (const int*)d_in[4];
    const int*   ed2  = (const int*)d_in[5];
    const int*   ed3  = (const int*)d_in[6];
    const float* W_msg = (const float*)d_in[7];
    const float* b_msg = (const float*)d_in[8];
    const float* W_ih  = (const float*)d_in[9];
    const float* W_hh  = (const float*)d_in[10];
    const float* b_ih  = (const float*)d_in[11];
    const float* b_hh  = (const float*)d_in[12];
    float* out = (float*)d_out;

    const size_t helems = (size_t)B * N * H;       // 8.39M

    // ws layout (~69.1 MB total)
    unsigned*       hp    = (unsigned*)d_ws;                              // 33.55 MB
    unsigned short* medge = (unsigned short*)(hp + helems);               // 33.55 MB (2 batches)
    __bf16*   Wmt   = (__bf16*)(medge + (size_t)2 * ET * E * H);          // 0.52 MB
    __bf16*   Wt    = Wmt + (size_t)ET * 16 * 8 * 64 * 8;                 // 0.79 MB
    int*      csrn  = (int*)(Wt + (size_t)6 * 16 * 8 * 64 * 8);           // 0.13 MB
    int*      eslot = csrn + (size_t)B * N;                               // 0.52 MB
    float*    gacc  = (float*)(eslot + (size_t)B * ET * E);               // 4 KB

    // ---- setup ----
    pack_kernel<<<dim3(helems / 4 / 256), 256, 0, stream>>>(emb, hp);
    wtrans_msg<<<dim3(128), 256, 0, stream>>>(W_msg, Wmt);
    wtrans_gate<<<dim3(192), 256, 0, stream>>>(W_ih, W_hh, Wt);
    hipMemsetAsync(csrn, 0, (size_t)B * N * sizeof(int), stream);
    countk2<<<dim3(B * ET * E / 256), 256, 0, stream>>>(ed0, ed1, ed2, ed3, csrn);
    scank<<<dim3(B), 256, 0, stream>>>(csrn);
    fillk2<<<dim3(B * ET * E / 256), 256, 0, stream>>>(ed0, ed1, ed2, ed3, csrn, eslot);

    // ---- T iterations, 2-batch chunks ----
    for (int t = 0; t < T_ITERS; ++t) {
        for (int bc = 0; bc < 2; ++bc) {
            msgk2<<<dim3(E / 64, 2 * ET), 256, 0, stream>>>(
                hp, ed0, ed1, ed2, ed3, eslot, Wmt, b_msg, medge, bc);
            gruk<<<dim3(2 * N / 16), 256, 0, stream>>>(
                medge, csrn, hp, Wt, b_ih, b_hh, bc);
        }
    }

    // ---- epilogue ----
    hipMemsetAsync(gacc, 0, (size_t)B * H * sizeof(float), stream);
    sel_kernel<<<dim3(B * M / 4), 256, 0, stream>>>(hp, nao, out);
    gmean_kernel<<<dim3(B * 16), 256, 0, stream>>>(out, gacc);
    final_kernel<<<dim3((B * M + B * H) / 256), 256, 0, stream>>>(gacc, out);
}